// Round 12
// baseline (78.431 us; speedup 1.0000x reference)
//
#include <hip/hip_runtime.h>
#include <math.h>

#define SEQ 4096
#define NH  8
#define DIM 64
// 32 (n,h) pairs total: n=4, h=8

__device__ __forceinline__ float elu1(float x) {
    // jax.nn.elu(x)+1: branchless — exp(min(x,0)) + max(x,0)
    return __expf(fminf(x, 0.0f)) + fmaxf(x, 0.0f);
}

// ---------------- Phase 1: partial KV (64x64) + partial Ksum per (n,h,chunk) ----------------
// R5 (dbuf, 16-row tiles: compute 512cyc < latency) and R11 (single-buf,
// 64-row tiles: latency exposed serially every tile) both pinned at ~38-39us.
// Neither ever had BOTH prefetch AND compute >= latency. This round: 64-row
// tiles (2248 cyc compute/wave) + DOUBLE BUFFER — tile t+1's 8 loads issue at
// the top of tile t's compute, elu+LDS-write to the alternate buffer after
// compute (vmcnt drained by then), ONE barrier per tile. LDS 64KB -> 2 blk/CU.
__global__ __launch_bounds__(256) void k_phase1(const float* __restrict__ Kin,
                                                const float* __restrict__ Vin,
                                                float* __restrict__ pKV,
                                                float* __restrict__ pKs,
                                                int NC, int sLen) {
    const int nh = blockIdx.x / NC;
    const int ck = blockIdx.x % NC;
    const int n  = nh >> 3, h = nh & 7;
    const int t  = threadIdx.x;
    const int r  = t >> 4;            // staging row 0..15
    const int c4 = (t & 15) * 4;      // staging col x4
    const int wv = t >> 6, lane = t & 63;
    const int d0 = (lane >> 3) * 8;   // owned d block (8)
    const int v0 = (lane & 7) * 8;    // owned v block (8)
    const int RS = NH * DIM;          // 512 floats per s-row

    __shared__ __align__(16) float kf[2][4096];  // 32 KB: elu'd K tiles [64][64]; [0]/[1] reused as reduce slots
    __shared__ __align__(16) float vv[2][4096];  // 32 KB: V tiles; [0] reused for ksum reduce

    float acc[8][8];
#pragma unroll
    for (int i = 0; i < 8; i++)
#pragma unroll
        for (int j = 0; j < 8; j++) acc[i][j] = 0.0f;
    float ksl[4] = {0.f, 0.f, 0.f, 0.f};

    const size_t base = ((size_t)(n * SEQ + ck * sLen) * NH + h) * DIM;
    const int ntiles = sLen >> 6;     // 4 at NC=16

    // prologue: stage tile 0 into buffer 0
    {
        const float* Kb = Kin + base + (size_t)r * RS + c4;
        const float* Vb = Vin + base + (size_t)r * RS + c4;
#pragma unroll
        for (int i = 0; i < 4; ++i) {
            float4 k4 = *(const float4*)(Kb + (size_t)(16 * i) * RS);
            float4 v4 = *(const float4*)(Vb + (size_t)(16 * i) * RS);
            float4 f4;
            f4.x = elu1(k4.x); f4.y = elu1(k4.y); f4.z = elu1(k4.z); f4.w = elu1(k4.w);
            ksl[0] += f4.x; ksl[1] += f4.y; ksl[2] += f4.z; ksl[3] += f4.w;
            *(float4*)&kf[0][(r + 16 * i) * 64 + c4] = f4;
            *(float4*)&vv[0][(r + 16 * i) * 64 + c4] = v4;
        }
    }

    int cur = 0;
    for (int tile = 0; tile < ntiles; ++tile) {
        __syncthreads();                      // buf[cur] staged; buf[cur^1] reads (tile-1 compute) done
        float4 kreg[4], vreg[4];
        const bool more = (tile + 1 < ntiles);
        if (more) {                           // issue next tile's 8 loads NOW — latency hides under compute
            const float* Kb = Kin + base + ((size_t)((tile + 1) * 64) + r) * RS + c4;
            const float* Vb = Vin + base + ((size_t)((tile + 1) * 64) + r) * RS + c4;
#pragma unroll
            for (int i = 0; i < 4; ++i) {
                kreg[i] = *(const float4*)(Kb + (size_t)(16 * i) * RS);
                vreg[i] = *(const float4*)(Vb + (size_t)(16 * i) * RS);
            }
        }
        // compute: each wave its 16 s-rows, 64 fma each
#pragma unroll 2
        for (int ssi = 0; ssi < 16; ++ssi) {
            const int ss = wv * 16 + ssi;
            float4 a0 = *(const float4*)&kf[cur][ss * 64 + d0];
            float4 a1 = *(const float4*)&kf[cur][ss * 64 + d0 + 4];
            float4 b0 = *(const float4*)&vv[cur][ss * 64 + v0];
            float4 b1 = *(const float4*)&vv[cur][ss * 64 + v0 + 4];
            float a[8] = {a0.x, a0.y, a0.z, a0.w, a1.x, a1.y, a1.z, a1.w};
            float b[8] = {b0.x, b0.y, b0.z, b0.w, b1.x, b1.y, b1.z, b1.w};
#pragma unroll
            for (int i = 0; i < 8; i++)
#pragma unroll
                for (int j = 0; j < 8; j++)
                    acc[i][j] = fmaf(a[i], b[j], acc[i][j]);
        }
        if (more) {                           // vmcnt drained by the 2248-cyc compute; write other buffer
#pragma unroll
            for (int i = 0; i < 4; ++i) {
                float4 f4;
                f4.x = elu1(kreg[i].x); f4.y = elu1(kreg[i].y);
                f4.z = elu1(kreg[i].z); f4.w = elu1(kreg[i].w);
                ksl[0] += f4.x; ksl[1] += f4.y; ksl[2] += f4.z; ksl[3] += f4.w;
                *(float4*)&kf[cur ^ 1][(r + 16 * i) * 64 + c4] = f4;
                *(float4*)&vv[cur ^ 1][(r + 16 * i) * 64 + c4] = vreg[i];
            }
            cur ^= 1;
        }
    }
    __syncthreads();    // all compute done; kf free for reduction

    // ---- acc tree-reduce 4 waves -> wave 0 (slots kf[0], kf[1]; layout elem*64+lane) ----
#define ACC_W(S) { _Pragma("unroll") for (int i_=0;i_<8;i_++) _Pragma("unroll") for (int j_=0;j_<8;j_++) (S)[(i_*8+j_)*64+lane]=acc[i_][j_]; }
#define ACC_A(S) { _Pragma("unroll") for (int i_=0;i_<8;i_++) _Pragma("unroll") for (int j_=0;j_<8;j_++) acc[i_][j_]+=(S)[(i_*8+j_)*64+lane]; }
    if (wv == 1) ACC_W(kf[0]);
    if (wv == 3) ACC_W(kf[1]);
    // ksum partials can go to vv[0] any time after the top barrier (vv only read in compute)
    *(float4*)&vv[0][r * 64 + c4] = make_float4(ksl[0], ksl[1], ksl[2], ksl[3]);
    __syncthreads();
    if (wv == 0) ACC_A(kf[0]);
    if (wv == 2) ACC_A(kf[1]);
    __syncthreads();
    if (wv == 2) ACC_W(kf[0]);
    __syncthreads();
    if (wv == 0) {
        ACC_A(kf[0]);
        const int pnh = n * 8 + h;
        float* dst = pKV + ((size_t)ck * 32 + pnh) * 4096;
#pragma unroll
        for (int i = 0; i < 8; i++) {
            float4 oa, ob;
            oa.x = acc[i][0]; oa.y = acc[i][1]; oa.z = acc[i][2]; oa.w = acc[i][3];
            ob.x = acc[i][4]; ob.y = acc[i][5]; ob.z = acc[i][6]; ob.w = acc[i][7];
            *(float4*)(dst + (d0 + i) * 64 + v0)     = oa;
            *(float4*)(dst + (d0 + i) * 64 + v0 + 4) = ob;
        }
    }
    if (t < 64) {   // ksum final (vv[0] writes all landed before the 2nd barrier above)
        float s = 0.0f;
#pragma unroll
        for (int rr = 0; rr < 16; ++rr) s += vv[0][rr * 64 + t];
        pKs[((size_t)ck * 32 + n * 8 + h) * 64 + t] = s;
    }
}

// ---------------- Reduce partials -> final KV, Ksum ----------------
template <int NC>
__global__ __launch_bounds__(128) void k_reduceT(const float* __restrict__ pKV,
                                                 const float* __restrict__ pKs,
                                                 float* __restrict__ KVf,
                                                 float* __restrict__ Ksf) {
    const int gid = blockIdx.x * 128 + threadIdx.x;   // 0..32767, one float4 each
    const float4* p4 = (const float4*)pKV;
    float4 s = make_float4(0.f, 0.f, 0.f, 0.f);
#pragma unroll
    for (int c = 0; c < NC; ++c) {
        float4 v = p4[(size_t)c * 32768 + gid];
        s.x += v.x; s.y += v.y; s.z += v.z; s.w += v.w;
    }
    ((float4*)KVf)[gid] = s;
    if (gid < 2048) {
        float ss = 0.0f;
#pragma unroll
        for (int c = 0; c < NC; ++c) ss += pKs[(size_t)c * 2048 + gid];
        Ksf[gid] = ss;
    }
}

__global__ __launch_bounds__(128) void k_reduceG(const float* __restrict__ pKV,
                                                 const float* __restrict__ pKs,
                                                 float* __restrict__ KVf,
                                                 float* __restrict__ Ksf, int NC) {
    const int gid = blockIdx.x * 128 + threadIdx.x;
    const float4* p4 = (const float4*)pKV;
    float4 s = make_float4(0.f, 0.f, 0.f, 0.f);
    for (int c = 0; c < NC; ++c) {
        float4 v = p4[(size_t)c * 32768 + gid];
        s.x += v.x; s.y += v.y; s.z += v.z; s.w += v.w;
    }
    ((float4*)KVf)[gid] = s;
    if (gid < 2048) {
        float ss = 0.0f;
        for (int c = 0; c < NC; ++c) ss += pKs[(size_t)c * 2048 + gid];
        Ksf[gid] = ss;
    }
}

// ---------------- Phase 2: register-tiled GEMM, out[l,v] = (Qf.KV[:,v]) / (Qf.Ks + eps) ----------------
// (R4/R5-benched version, ~14us: 512 blocks, 8x8 per-thread tile, Qt chunked
// to 16 d-rows, swizzle col = row ^ (dl&12) -> <=2-way on writes and reads.)
__global__ __launch_bounds__(256) void k_phase2(const float* __restrict__ Qin,
                                                const float* __restrict__ KVf,
                                                const float* __restrict__ Ksf,
                                                float* __restrict__ Out) {
    const int nh   = blockIdx.x >> 4;
    const int tile = blockIdx.x & 15;
    const int n = nh >> 3, h = nh & 7;
    const int t = threadIdx.x;

    __shared__ __align__(16) float Qt[16 * 256];   // 16 KB, swizzled transpose chunk
    __shared__ __align__(16) float KVs[64][64];    // 16 KB
    __shared__ float Kss[64];

    // stage KV + Ksum (coalesced; small, L2/L3-resident)
    {
        const float4* src = (const float4*)(KVf + (size_t)nh * 4096);
        float4* dst = (float4*)&KVs[0][0];
#pragma unroll
        for (int i = 0; i < 4; ++i) dst[t + 256 * i] = src[t + 256 * i];
        if (t < 64) Kss[t] = Ksf[nh * 64 + t];
    }

    const int l0 = tile * 256;
    const int r0 = (t >> 3) * 8;     // owned rows (8), 0..248
    const int v0 = (t & 7) * 8;      // owned cols (8)

    float acc[8][8];
#pragma unroll
    for (int i = 0; i < 8; i++)
#pragma unroll
        for (int j = 0; j < 8; j++) acc[i][j] = 0.0f;
    float p[8] = {0.f, 0.f, 0.f, 0.f, 0.f, 0.f, 0.f, 0.f};

    for (int dc = 0; dc < 4; ++dc) {
        if (dc) __syncthreads();       // protect Qt before overwrite
        // stage Q chunk (16 d) transposed+swizzled: 1024 float4
#pragma unroll
        for (int i = 0; i < 4; ++i) {
            const int j   = t + 256 * i;
            const int row = j >> 2;           // 0..255
            const int dl4 = (j & 3) << 2;     // local d f4-group: 0,4,8,12
            const size_t g = ((size_t)(n * SEQ + l0 + row) * NH + h) * DIM + dc * 16 + dl4;
            float4 q4 = *(const float4*)(Qin + g);
            const int col = row ^ dl4;
            Qt[(dl4 + 0) * 256 + col] = elu1(q4.x);
            Qt[(dl4 + 1) * 256 + col] = elu1(q4.y);
            Qt[(dl4 + 2) * 256 + col] = elu1(q4.z);
            Qt[(dl4 + 3) * 256 + col] = elu1(q4.w);
        }
        __syncthreads();

#pragma unroll 2
        for (int dl = 0; dl < 16; ++dl) {
            const int d = dc * 16 + dl;
            const int s = dl & 12;
            float4 qa = *(const float4*)&Qt[dl * 256 + (r0 ^ s)];
            float4 qb = *(const float4*)&Qt[dl * 256 + ((r0 + 4) ^ s)];
            float4 ka = *(const float4*)&KVs[d][v0];
            float4 kb = *(const float4*)&KVs[d][v0 + 4];
            const float ksd = Kss[d];
            float q[8]  = {qa.x, qa.y, qa.z, qa.w, qb.x, qb.y, qb.z, qb.w};
            float kv[8] = {ka.x, ka.y, ka.z, ka.w, kb.x, kb.y, kb.z, kb.w};
#pragma unroll
            for (int i = 0; i < 8; ++i) {
                p[i] = fmaf(q[i], ksd, p[i]);
#pragma unroll
                for (int jj = 0; jj < 8; ++jj)
                    acc[i][jj] = fmaf(q[i], kv[jj], acc[i][jj]);
            }
        }
    }

    // epilogue: scale by 1/(p+eps), float4 stores
#pragma unroll
    for (int i = 0; i < 8; ++i) {
        const float z = 1.0f / (p[i] + 1e-6f);
        const int l = l0 + r0 + i;
        float* o = Out + ((size_t)(n * SEQ + l) * NH + h) * DIM + v0;
        float4 oa, ob;
        oa.x = acc[i][0] * z; oa.y = acc[i][1] * z; oa.z = acc[i][2] * z; oa.w = acc[i][3] * z;
        ob.x = acc[i][4] * z; ob.y = acc[i][5] * z; ob.z = acc[i][6] * z; ob.w = acc[i][7] * z;
        *(float4*)(o)     = oa;
        *(float4*)(o + 4) = ob;
    }
}

extern "C" void kernel_launch(void* const* d_in, const int* in_sizes, int n_in,
                              void* d_out, int out_size, void* d_ws, size_t ws_size,
                              hipStream_t stream) {
    const float* Q = (const float*)d_in[0];
    const float* K = (const float*)d_in[1];
    const float* V = (const float*)d_in[2];
    float* out = (float*)d_out;

    // ws layout: [KVf 32*4096][Ksf 32*64][pKV NC*32*4096][pKs NC*32*64]
    int NC = 16;  // grid = 32*NC = 512 blocks of 256 thr -> 2 blocks/CU (LDS-capped)
    const size_t unit = 133120ull * 4ull; // (4096+64)*32 floats in bytes
    while (NC > 1 && (size_t)(NC + 1) * unit > ws_size) NC >>= 1;
    const int sLen = SEQ / NC;

    float* KVf = (float*)d_ws;
    float* Ksf = KVf + 32 * 4096;
    float* pKV = Ksf + 32 * 64;
    float* pKs = pKV + (size_t)NC * 32 * 4096;

    hipLaunchKernelGGL(k_phase1, dim3(32 * NC), dim3(256), 0, stream, K, V, pKV, pKs, NC, sLen);
    switch (NC) {
        case 16: hipLaunchKernelGGL(k_reduceT<16>, dim3(256), dim3(128), 0, stream, pKV, pKs, KVf, Ksf); break;
        case 8:  hipLaunchKernelGGL(k_reduceT<8>,  dim3(256), dim3(128), 0, stream, pKV, pKs, KVf, Ksf); break;
        case 4:  hipLaunchKernelGGL(k_reduceT<4>,  dim3(256), dim3(128), 0, stream, pKV, pKs, KVf, Ksf); break;
        default: hipLaunchKernelGGL(k_reduceG, dim3(256), dim3(128), 0, stream, pKV, pKs, KVf, Ksf, NC); break;
    }
    hipLaunchKernelGGL(k_phase2, dim3(512), dim3(256), 0, stream, Q, KVf, Ksf, out);
}

// Round 13
// 65.182 us; speedup vs baseline: 1.2033x; 1.2033x over previous
//
#include <hip/hip_runtime.h>
#include <math.h>

#define SEQ 4096
#define NH  8
#define DIM 64
// 32 (n,h) pairs total: n=4, h=8

__device__ __forceinline__ float elu1(float x) {
    // jax.nn.elu(x)+1: branchless — exp(min(x,0)) + max(x,0)
    return __expf(fminf(x, 0.0f)) + fmaxf(x, 0.0f);
}

// DMA 16B/lane global->LDS. LDS dest is wave-uniform base + lane*16;
// global src is per-lane. Zero VGPR round-trip (R12's failure was regalloc
// sinking reg-staged prefetch: 64-reg acc left no headroom).
__device__ __forceinline__ void gload16(const float* g, float* l) {
    __builtin_amdgcn_global_load_lds(
        (const __attribute__((address_space(1))) float*)g,
        (__attribute__((address_space(3))) float*)l, 16, 0, 0);
}

// ---------------- Phase 1: partial KV (64x64) + partial Ksum per (n,h,chunk) ----------------
// Double-buffered 64-row tiles staged via global_load_lds DMA: tile t+1's
// DMA issues right after the barrier and runs concurrently with tile t's
// 2048-cyc compute; each wave's next barrier drains its own DMA (vmcnt).
// elu applied at compute time (K read broadcast by 8 lanes, 8 elu/64 fma).
// Per wave per tile: 4 K-DMA + 4 V-DMA instructions (1KB each, 16 rows).
__global__ __launch_bounds__(256) void k_phase1(const float* __restrict__ Kin,
                                                const float* __restrict__ Vin,
                                                float* __restrict__ pKV,
                                                float* __restrict__ pKs,
                                                int NC, int sLen) {
    const int nh = blockIdx.x / NC;
    const int ck = blockIdx.x % NC;
    const int n  = nh >> 3, h = nh & 7;
    const int t  = threadIdx.x;
    const int wv = t >> 6, lane = t & 63;
    const int d0 = (lane >> 3) * 8;   // owned d block (8)
    const int v0 = (lane & 7) * 8;    // owned v block (8)
    const int RS = NH * DIM;          // 512 floats per s-row

    __shared__ __align__(16) float kf[2][4096];  // 32 KB: raw K tiles [64][64]; reused as acc-reduce slots
    __shared__ __align__(16) float vv[2][4096];  // 32 KB: V tiles; vv[0] reused for ksum reduce

    float acc[8][8];
#pragma unroll
    for (int i = 0; i < 8; i++)
#pragma unroll
        for (int j = 0; j < 8; j++) acc[i][j] = 0.0f;
    float ks[8] = {0.f, 0.f, 0.f, 0.f, 0.f, 0.f, 0.f, 0.f};

    const size_t base = ((size_t)(n * SEQ + ck * sLen) * NH + h) * DIM;
    // per-lane global src for this wave's 16 staging rows (4 rows per DMA instr)
    const float* Kt = Kin + base + ((size_t)(wv * 16) + (lane >> 4)) * RS + (lane & 15) * 4;
    const float* Vt = Vin + base + ((size_t)(wv * 16) + (lane >> 4)) * RS + (lane & 15) * 4;
    const int ntiles = sLen >> 6;     // 4 at NC=16

#define STAGE(TI, BUF) do {                                                   \
    const size_t roff_ = (size_t)(TI) * 64 * RS;                              \
    _Pragma("unroll")                                                         \
    for (int i_ = 0; i_ < 4; ++i_) {                                          \
        gload16(Kt + roff_ + (size_t)(4 * i_) * RS,                           \
                &kf[BUF][(wv * 16 + 4 * i_) * 64]);                           \
        gload16(Vt + roff_ + (size_t)(4 * i_) * RS,                           \
                &vv[BUF][(wv * 16 + 4 * i_) * 64]);                           \
    }                                                                         \
} while (0)

    STAGE(0, 0);                       // prologue: tile 0 -> buf 0
    for (int tile = 0; tile < ntiles; ++tile) {
        const int cur = tile & 1;
        __syncthreads();               // drains own DMA -> buf[cur] staged; prior compute done
        if (tile + 1 < ntiles)
            STAGE(tile + 1, cur ^ 1);  // DMA runs under this tile's compute, zero VGPRs
        // compute: each wave its 16 s-rows, elu on K at read time
#pragma unroll 2
        for (int ssi = 0; ssi < 16; ++ssi) {
            const int ss = wv * 16 + ssi;
            float4 a0 = *(const float4*)&kf[cur][ss * 64 + d0];
            float4 a1 = *(const float4*)&kf[cur][ss * 64 + d0 + 4];
            float4 b0 = *(const float4*)&vv[cur][ss * 64 + v0];
            float4 b1 = *(const float4*)&vv[cur][ss * 64 + v0 + 4];
            float a[8] = {elu1(a0.x), elu1(a0.y), elu1(a0.z), elu1(a0.w),
                          elu1(a1.x), elu1(a1.y), elu1(a1.z), elu1(a1.w)};
            float b[8] = {b0.x, b0.y, b0.z, b0.w, b1.x, b1.y, b1.z, b1.w};
#pragma unroll
            for (int i = 0; i < 8; i++) ks[i] += a[i];
#pragma unroll
            for (int i = 0; i < 8; i++)
#pragma unroll
                for (int j = 0; j < 8; j++)
                    acc[i][j] = fmaf(a[i], b[j], acc[i][j]);
        }
    }
    __syncthreads();    // all compute done; kf/vv free for reduction

    // ---- acc tree-reduce 4 waves -> wave 0 (slots kf[0], kf[1]; layout elem*64+lane) ----
#define ACC_W(S) { _Pragma("unroll") for (int i_=0;i_<8;i_++) _Pragma("unroll") for (int j_=0;j_<8;j_++) (S)[(i_*8+j_)*64+lane]=acc[i_][j_]; }
#define ACC_A(S) { _Pragma("unroll") for (int i_=0;i_<8;i_++) _Pragma("unroll") for (int j_=0;j_<8;j_++) acc[i_][j_]+=(S)[(i_*8+j_)*64+lane]; }
    if (wv == 1) ACC_W(kf[0]);
    if (wv == 3) ACC_W(kf[1]);
    // ksum partials: one lane per d-group holds the exact per-wave sum (8 lanes duplicate)
    if ((lane & 7) == 0) {
#pragma unroll
        for (int i = 0; i < 8; i++) vv[0][wv * 64 + d0 + i] = ks[i];
    }
    __syncthreads();
    if (wv == 0) ACC_A(kf[0]);
    if (wv == 2) ACC_A(kf[1]);
    __syncthreads();
    if (wv == 2) ACC_W(kf[0]);
    __syncthreads();
    if (wv == 0) {
        ACC_A(kf[0]);
        const int pnh = n * 8 + h;
        float* dst = pKV + ((size_t)ck * 32 + pnh) * 4096;
#pragma unroll
        for (int i = 0; i < 8; i++) {
            float4 oa, ob;
            oa.x = acc[i][0]; oa.y = acc[i][1]; oa.z = acc[i][2]; oa.w = acc[i][3];
            ob.x = acc[i][4]; ob.y = acc[i][5]; ob.z = acc[i][6]; ob.w = acc[i][7];
            *(float4*)(dst + (d0 + i) * 64 + v0)     = oa;
            *(float4*)(dst + (d0 + i) * 64 + v0 + 4) = ob;
        }
    }
    if (t < 64) {   // ksum final: 4 wave partials (written before 1st reduce barrier)
        float s = vv[0][t] + vv[0][64 + t] + vv[0][128 + t] + vv[0][192 + t];
        pKs[((size_t)ck * 32 + n * 8 + h) * 64 + t] = s;
    }
}

// ---------------- Reduce partials -> final KV, Ksum ----------------
template <int NC>
__global__ __launch_bounds__(128) void k_reduceT(const float* __restrict__ pKV,
                                                 const float* __restrict__ pKs,
                                                 float* __restrict__ KVf,
                                                 float* __restrict__ Ksf) {
    const int gid = blockIdx.x * 128 + threadIdx.x;   // 0..32767, one float4 each
    const float4* p4 = (const float4*)pKV;
    float4 s = make_float4(0.f, 0.f, 0.f, 0.f);
#pragma unroll
    for (int c = 0; c < NC; ++c) {
        float4 v = p4[(size_t)c * 32768 + gid];
        s.x += v.x; s.y += v.y; s.z += v.z; s.w += v.w;
    }
    ((float4*)KVf)[gid] = s;
    if (gid < 2048) {
        float ss = 0.0f;
#pragma unroll
        for (int c = 0; c < NC; ++c) ss += pKs[(size_t)c * 2048 + gid];
        Ksf[gid] = ss;
    }
}

__global__ __launch_bounds__(128) void k_reduceG(const float* __restrict__ pKV,
                                                 const float* __restrict__ pKs,
                                                 float* __restrict__ KVf,
                                                 float* __restrict__ Ksf, int NC) {
    const int gid = blockIdx.x * 128 + threadIdx.x;
    const float4* p4 = (const float4*)pKV;
    float4 s = make_float4(0.f, 0.f, 0.f, 0.f);
    for (int c = 0; c < NC; ++c) {
        float4 v = p4[(size_t)c * 32768 + gid];
        s.x += v.x; s.y += v.y; s.z += v.z; s.w += v.w;
    }
    ((float4*)KVf)[gid] = s;
    if (gid < 2048) {
        float ss = 0.0f;
        for (int c = 0; c < NC; ++c) ss += pKs[(size_t)c * 2048 + gid];
        Ksf[gid] = ss;
    }
}

// ---------------- Phase 2: register-tiled GEMM, out[l,v] = (Qf.KV[:,v]) / (Qf.Ks + eps) ----------------
// (R4/R5-benched version, ~14us: 512 blocks, 8x8 per-thread tile, Qt chunked
// to 16 d-rows, swizzle col = row ^ (dl&12) -> <=2-way on writes and reads.)
__global__ __launch_bounds__(256) void k_phase2(const float* __restrict__ Qin,
                                                const float* __restrict__ KVf,
                                                const float* __restrict__ Ksf,
                                                float* __restrict__ Out) {
    const int nh   = blockIdx.x >> 4;
    const int tile = blockIdx.x & 15;
    const int n = nh >> 3, h = nh & 7;
    const int t = threadIdx.x;

    __shared__ __align__(16) float Qt[16 * 256];   // 16 KB, swizzled transpose chunk
    __shared__ __align__(16) float KVs[64][64];    // 16 KB
    __shared__ float Kss[64];

    // stage KV + Ksum (coalesced; small, L2/L3-resident)
    {
        const float4* src = (const float4*)(KVf + (size_t)nh * 4096);
        float4* dst = (float4*)&KVs[0][0];
#pragma unroll
        for (int i = 0; i < 4; ++i) dst[t + 256 * i] = src[t + 256 * i];
        if (t < 64) Kss[t] = Ksf[nh * 64 + t];
    }

    const int l0 = tile * 256;
    const int r0 = (t >> 3) * 8;     // owned rows (8), 0..248
    const int v0 = (t & 7) * 8;      // owned cols (8)

    float acc[8][8];
#pragma unroll
    for (int i = 0; i < 8; i++)
#pragma unroll
        for (int j = 0; j < 8; j++) acc[i][j] = 0.0f;
    float p[8] = {0.f, 0.f, 0.f, 0.f, 0.f, 0.f, 0.f, 0.f};

    for (int dc = 0; dc < 4; ++dc) {
        if (dc) __syncthreads();       // protect Qt before overwrite
        // stage Q chunk (16 d) transposed+swizzled: 1024 float4
#pragma unroll
        for (int i = 0; i < 4; ++i) {
            const int j   = t + 256 * i;
            const int row = j >> 2;           // 0..255
            const int dl4 = (j & 3) << 2;     // local d f4-group: 0,4,8,12
            const size_t g = ((size_t)(n * SEQ + l0 + row) * NH + h) * DIM + dc * 16 + dl4;
            float4 q4 = *(const float4*)(Qin + g);
            const int col = row ^ dl4;
            Qt[(dl4 + 0) * 256 + col] = elu1(q4.x);
            Qt[(dl4 + 1) * 256 + col] = elu1(q4.y);
            Qt[(dl4 + 2) * 256 + col] = elu1(q4.z);
            Qt[(dl4 + 3) * 256 + col] = elu1(q4.w);
        }
        __syncthreads();

#pragma unroll 2
        for (int dl = 0; dl < 16; ++dl) {
            const int d = dc * 16 + dl;
            const int s = dl & 12;
            float4 qa = *(const float4*)&Qt[dl * 256 + (r0 ^ s)];
            float4 qb = *(const float4*)&Qt[dl * 256 + ((r0 + 4) ^ s)];
            float4 ka = *(const float4*)&KVs[d][v0];
            float4 kb = *(const float4*)&KVs[d][v0 + 4];
            const float ksd = Kss[d];
            float q[8]  = {qa.x, qa.y, qa.z, qa.w, qb.x, qb.y, qb.z, qb.w};
            float kv[8] = {ka.x, ka.y, ka.z, ka.w, kb.x, kb.y, kb.z, kb.w};
#pragma unroll
            for (int i = 0; i < 8; ++i) {
                p[i] = fmaf(q[i], ksd, p[i]);
#pragma unroll
                for (int jj = 0; jj < 8; ++jj)
                    acc[i][jj] = fmaf(q[i], kv[jj], acc[i][jj]);
            }
        }
    }

    // epilogue: scale by 1/(p+eps), float4 stores
#pragma unroll
    for (int i = 0; i < 8; ++i) {
        const float z = 1.0f / (p[i] + 1e-6f);
        const int l = l0 + r0 + i;
        float* o = Out + ((size_t)(n * SEQ + l) * NH + h) * DIM + v0;
        float4 oa, ob;
        oa.x = acc[i][0] * z; oa.y = acc[i][1] * z; oa.z = acc[i][2] * z; oa.w = acc[i][3] * z;
        ob.x = acc[i][4] * z; ob.y = acc[i][5] * z; ob.z = acc[i][6] * z; ob.w = acc[i][7] * z;
        *(float4*)(o)     = oa;
        *(float4*)(o + 4) = ob;
    }
}

extern "C" void kernel_launch(void* const* d_in, const int* in_sizes, int n_in,
                              void* d_out, int out_size, void* d_ws, size_t ws_size,
                              hipStream_t stream) {
    const float* Q = (const float*)d_in[0];
    const float* K = (const float*)d_in[1];
    const float* V = (const float*)d_in[2];
    float* out = (float*)d_out;

    // ws layout: [KVf 32*4096][Ksf 32*64][pKV NC*32*4096][pKs NC*32*64]
    int NC = 16;  // grid = 32*NC = 512 blocks of 256 thr -> 2 blocks/CU (LDS 64KB)
    const size_t unit = 133120ull * 4ull; // (4096+64)*32 floats in bytes
    while (NC > 1 && (size_t)(NC + 1) * unit > ws_size) NC >>= 1;
    const int sLen = SEQ / NC;

    float* KVf = (float*)d_ws;
    float* Ksf = KVf + 32 * 4096;
    float* pKV = Ksf + 32 * 64;
    float* pKs = pKV + (size_t)NC * 32 * 4096;

    hipLaunchKernelGGL(k_phase1, dim3(32 * NC), dim3(256), 0, stream, K, V, pKV, pKs, NC, sLen);
    switch (NC) {
        case 16: hipLaunchKernelGGL(k_reduceT<16>, dim3(256), dim3(128), 0, stream, pKV, pKs, KVf, Ksf); break;
        case 8:  hipLaunchKernelGGL(k_reduceT<8>,  dim3(256), dim3(128), 0, stream, pKV, pKs, KVf, Ksf); break;
        case 4:  hipLaunchKernelGGL(k_reduceT<4>,  dim3(256), dim3(128), 0, stream, pKV, pKs, KVf, Ksf); break;
        default: hipLaunchKernelGGL(k_reduceG, dim3(256), dim3(128), 0, stream, pKV, pKs, KVf, Ksf, NC); break;
    }
    hipLaunchKernelGGL(k_phase2, dim3(512), dim3(256), 0, stream, Q, KVf, Ksf, out);
}